// Round 3
// baseline (2034.534 us; speedup 1.0000x reference)
//
#include <hip/hip_runtime.h>

// GRU scan: T=512, B=64, D=H=512.  out[t] = h_{t+1}, fp32 [T,B,H].
//
//  K1 prep:   cast x->bf16, transpose+cast Wi,Wh -> [3H][K] bf16, init Hseq[0], zero bar
//  K2 gi_gemm: Gi[T*B,3H] = Xb @ Wi + bi  (bf16 MFMA, 128x128 tiles), stored bf16
//  K3 recurrent: 4 independent clusters of 8 WGs (batch rows are independent).
//     Cluster c owns batch rows [16c,16c+16); WG slot s owns cols [64s,64s+64), each
//     wave a distinct 16-col slice of Wh in registers.  R3 changes:
//       - NO LDS staging: A-fragments load straight from the peer h block in the
//         cluster's XCD L2 (b128). L1 de-duplicates across the WG's 4 waves; every
//         step uses a fresh buffer address so L1 is never stale (own-written lines
//         hold own data, peer lines are first-touch).
//       - Gi prefetch is a parity double-buffer of RAW ushorts (giA/giB), issued
//         AFTER the flag store and consumed at the NEXT step's gates -> HBM/L3
//         latency hidden under poll+A-load+MFMA; pre-flag __syncthreads drains only
//         the 2KB h stores.
//     Sync: 8 distributed flag lines per cluster, wave0 lanes 0..7 parallel
//     CAS(want,want) poll.  Probe verifies same-L2 coherence; timeout -> agent-scope
//     fallback (proven R2 mechanics, same tiling).

#define T_STEPS 512
#define NWORK 32
#define CWG 8                 // WGs per cluster
#define NCL 4                 // clusters
#define NB_LAUNCH 256
#define FSTRIDE 16            // ints between flag lines (64 B)

typedef __attribute__((ext_vector_type(8))) short bhalf8;
typedef __attribute__((ext_vector_type(4))) float floatx4;

__device__ inline float bf2f(unsigned short u) {
  union { unsigned u; float f; } v; v.u = ((unsigned)u) << 16; return v.f;
}
__device__ inline unsigned short f2bf(float f) {
  union { float f; unsigned u; } v; v.f = f;
  unsigned x = v.u;
  return (unsigned short)((x + 0x7fffu + ((x >> 16) & 1u)) >> 16);
}

// ---- workspace layout (bytes) ----
// bar ints (prep zeroes 1024):
//   fflag lines:  (c*8+s)*16, c<4,s<8  -> ints [0,512)
//   flags[32] (fallback, agent): [512,544)
//   tick[8]@544, arrived@552, tick2@553, abortf@555, arrive2@556
//   pcnt lines: 576 + c*16  (c<4)
#define O_BAR 0                    //  4096 B
#define O_HB  4096                 //  Hseq[0] = h0 cast: [64][512] bf16 = 65536
#define O_WIT 69632                //  WiT [1536][512] bf16 = 1572864
#define O_WHT 1642496              //  WhT [1536][512] bf16 = 1572864
#define O_GI  3215360              //  Gi [32768][1536] bf16 = 100663296
#define O_XB  103878656ULL         //  Xb [32768][512] bf16 = 33554432 ; after K2 dies,
                                   //  reused as Hseq[1..512] (512 x 65536 B)
#define WS_NEED 137433088ULL       //  ~131.1 MiB

__device__ inline unsigned short* HS(char* ws, int t) {   // h buffer for step t
  return (t == 0) ? (unsigned short*)(ws + O_HB)
                  : (unsigned short*)(ws + O_XB + (long)(t - 1) * 65536);
}

// ---------------- K1: prep ----------------
__global__ void prep_kernel(const float* __restrict__ x, const float* __restrict__ h0,
                            const float* __restrict__ Wi, const float* __restrict__ Wh,
                            char* __restrict__ ws) {
  unsigned short* Xb  = (unsigned short*)(ws + O_XB);
  unsigned short* WiT = (unsigned short*)(ws + O_WIT);
  unsigned short* WhT = (unsigned short*)(ws + O_WHT);
  unsigned short* Hb0 = (unsigned short*)(ws + O_HB);
  int* bar = (int*)(ws + O_BAR);
  const long NX = 16777216, NW = 786432, NH = 32768;
  const long total = NX + 2 * NW + NH + 1024;
  for (long i = (long)blockIdx.x * blockDim.x + threadIdx.x; i < total;
       i += (long)gridDim.x * blockDim.x) {
    if (i < NX) {
      Xb[i] = f2bf(x[i]);
    } else if (i < NX + NW) {
      long j = i - NX;                 // j = n*512 + k  (WiT[n][k] = Wi[k][n])
      long n = j >> 9, k = j & 511;
      WiT[j] = f2bf(Wi[k * 1536 + n]);
    } else if (i < NX + 2 * NW) {
      long j = i - NX - NW;
      long n = j >> 9, k = j & 511;
      WhT[j] = f2bf(Wh[k * 1536 + n]);
    } else if (i < NX + 2 * NW + NH) {
      long j = i - NX - 2 * NW;
      Hb0[j] = f2bf(h0[j]);
    } else {
      bar[i - (NX + 2 * NW + NH)] = 0;
    }
  }
}

// ---------------- K2: Gi = Xb @ Wi + bi  (bf16 -> bf16) ----------------
__global__ void gi_gemm(const unsigned short* __restrict__ Xb,
                        const unsigned short* __restrict__ WiT,
                        const float* __restrict__ bi,
                        unsigned short* __restrict__ Gi) {
  __shared__ unsigned short As[128 * 32];
  __shared__ unsigned short Bs[128 * 32];
  const int tid  = threadIdx.x;
  const int m0   = blockIdx.x * 128;
  const int n0   = blockIdx.y * 128;
  const int lane = tid & 63, wv = tid >> 6;
  const int quad = lane >> 4, l16 = lane & 15;
  const int wm = (wv & 1) * 64, wn = (wv >> 1) * 64;
  const int sr = tid >> 1, sc = (tid & 1) * 16;

  floatx4 acc[4][4] = {};

  for (int kb = 0; kb < 16; ++kb) {
    const int k0 = kb * 32;
    __syncthreads();
    *(bhalf8*)(&As[sr * 32 + sc])     = *(const bhalf8*)(&Xb[(long)(m0 + sr) * 512 + k0 + sc]);
    *(bhalf8*)(&As[sr * 32 + sc + 8]) = *(const bhalf8*)(&Xb[(long)(m0 + sr) * 512 + k0 + sc + 8]);
    *(bhalf8*)(&Bs[sr * 32 + sc])     = *(const bhalf8*)(&WiT[(long)(n0 + sr) * 512 + k0 + sc]);
    *(bhalf8*)(&Bs[sr * 32 + sc + 8]) = *(const bhalf8*)(&WiT[(long)(n0 + sr) * 512 + k0 + sc + 8]);
    __syncthreads();

    bhalf8 af[4], bf[4];
#pragma unroll
    for (int i = 0; i < 4; ++i)
      af[i] = *(const bhalf8*)(&As[(wm + i * 16 + l16) * 32 + quad * 8]);
#pragma unroll
    for (int j = 0; j < 4; ++j)
      bf[j] = *(const bhalf8*)(&Bs[(wn + j * 16 + l16) * 32 + quad * 8]);
#pragma unroll
    for (int i = 0; i < 4; ++i)
#pragma unroll
      for (int j = 0; j < 4; ++j)
        acc[i][j] = __builtin_amdgcn_mfma_f32_16x16x32_bf16(af[i], bf[j], acc[i][j], 0, 0, 0);
  }

#pragma unroll
  for (int i = 0; i < 4; ++i)
#pragma unroll
    for (int j = 0; j < 4; ++j) {
      const int col = n0 + wn + j * 16 + l16;
      const float bv = bi[col];
#pragma unroll
      for (int r = 0; r < 4; ++r) {
        const int row = m0 + wm + i * 16 + quad * 4 + r;
        Gi[(long)row * 1536 + col] = f2bf(acc[i][j][r] + bv);
      }
    }
}

// ---- one GRU time step (macro so CUR_/NXT_ keep static register indexing) ----
#define GRU_STEP(T_, CUR_, NXT_) do {                                              \
    const int t_ = (T_);                                                           \
    const unsigned short* hin  = HS(ws, t_);                                       \
    unsigned short*       hout = HS(ws, t_ + 1);                                   \
    const unsigned short* ap = hin + (cluster * 16 + l16) * 512 + quad * 8;        \
    bhalf8 af[16];                                                                 \
    if (fast) {                                                                    \
      _Pragma("unroll")                                                            \
      for (int ks = 0; ks < 16; ++ks)                                              \
        af[ks] = *(const bhalf8*)(ap + ks * 32);   /* L1-shared, L2-fresh */       \
    } else {                                                                       \
      _Pragma("unroll")                                                            \
      for (int ks = 0; ks < 16; ++ks) {                                            \
        union { unsigned long long q[2]; bhalf8 v; } u;                            \
        u.q[0] = __hip_atomic_load((const unsigned long long*)(ap + ks * 32),      \
                                   __ATOMIC_RELAXED, __HIP_MEMORY_SCOPE_AGENT);    \
        u.q[1] = __hip_atomic_load((const unsigned long long*)(ap + ks * 32) + 1,  \
                                   __ATOMIC_RELAXED, __HIP_MEMORY_SCOPE_AGENT);    \
        af[ks] = u.v;                                                              \
      }                                                                            \
    }                                                                              \
    floatx4 racc = {0.f, 0.f, 0.f, 0.f};                                           \
    floatx4 zacc = {0.f, 0.f, 0.f, 0.f};                                           \
    floatx4 nacc = {0.f, 0.f, 0.f, 0.f};                                           \
    _Pragma("unroll")                                                              \
    for (int ks = 0; ks < 16; ++ks) {                                              \
      racc = __builtin_amdgcn_mfma_f32_16x16x32_bf16(af[ks], Bf[0][ks], racc, 0, 0, 0);\
      zacc = __builtin_amdgcn_mfma_f32_16x16x32_bf16(af[ks], Bf[1][ks], zacc, 0, 0, 0);\
      nacc = __builtin_amdgcn_mfma_f32_16x16x32_bf16(af[ks], Bf[2][ks], nacc, 0, 0, 0);\
    }                                                                              \
    _Pragma("unroll")                                                              \
    for (int r = 0; r < 4; ++r) {                                                  \
      const float rg = 1.f / (1.f + __expf(-(bf2f(CUR_[r]) + racc[r])));           \
      const float zg = 1.f / (1.f + __expf(-(bf2f(CUR_[4 + r]) + zacc[r])));       \
      const float pre = bf2f(CUR_[8 + r]) + rg * (nacc[r] + bhn_v);                \
      const float e2 = __expf(2.f * pre);                                          \
      const float ng = 1.f - 2.f / (e2 + 1.f);      /* tanh */                     \
      const float hn = (1.f - zg) * ng + zg * hprev[r];                            \
      hprev[r] = hn;                                                               \
      const unsigned hb = (unsigned)f2bf(hn);                                      \
      const unsigned ob = __shfl_xor(hb, 1, 64);    /* partner col (l16^1) */      \
      if (!(l16 & 1)) {                                                            \
        unsigned* dst = (unsigned*)(hout + (brow0 + r) * 512 + gcol);              \
        const unsigned packed = hb | (ob << 16);                                   \
        if (fast) *dst = packed;                    /* write-through -> XCD L2 */  \
        else __hip_atomic_store(dst, packed, __ATOMIC_RELAXED,                     \
                                __HIP_MEMORY_SCOPE_AGENT);                         \
      }                                                                            \
    }                                                                              \
    if (t_ + 1 < T_STEPS) {                                                        \
      const int want = t_ + 1;                                                     \
      if (fast) {                                                                  \
        __syncthreads();               /* drains ONLY the 2KB h stores */          \
        if (tid == 0)                                                              \
          __hip_atomic_store(&fflag[(cluster * CWG + slot) * FSTRIDE], want,       \
                             __ATOMIC_RELAXED, __HIP_MEMORY_SCOPE_WORKGROUP);      \
        /* fire-and-forget: out stores + next-step Gi overlap the poll and more */ \
        _Pragma("unroll")                                                          \
        for (int r = 0; r < 4; ++r)                                                \
          out[((long)t_ * 64 + brow0 + r) * 512 + gcol] = hprev[r];                \
        {                                                                          \
          const long gibase = (long)want * 64 * 1536;                              \
          _Pragma("unroll")                                                        \
          for (int r = 0; r < 4; ++r) {                                            \
            const long gb = gibase + (long)(brow0 + r) * 1536 + gcol;              \
            NXT_[r]     = Gi[gb];          /* raw ushorts: waitcnt lands at */     \
            NXT_[4 + r] = Gi[gb + 512];    /* NEXT step's gates            */      \
            NXT_[8 + r] = Gi[gb + 1024];                                           \
          }                                                                        \
        }                                                                          \
        if (tid < 64) {                                                            \
          bool ok = (lane >= CWG);                                                 \
          while (!__all(ok)) {                                                     \
            if (!ok) {                                                             \
              int exp = want;                                                      \
              __hip_atomic_compare_exchange_strong(                                \
                  &fflag[(cluster * CWG + lane) * FSTRIDE], &exp, want,            \
                  __ATOMIC_RELAXED, __ATOMIC_RELAXED,                              \
                  __HIP_MEMORY_SCOPE_WORKGROUP);                                   \
              ok = (exp >= want);                                                  \
            }                                                                      \
          }                                                                        \
        }                                                                          \
        __syncthreads();               /* release waves 1..3 */                    \
      } else {                                                                     \
        _Pragma("unroll")                                                          \
        for (int r = 0; r < 4; ++r)                                                \
          out[((long)t_ * 64 + brow0 + r) * 512 + gcol] = hprev[r];                \
        {                                                                          \
          const long gibase = (long)want * 64 * 1536;                              \
          _Pragma("unroll")                                                        \
          for (int r = 0; r < 4; ++r) {                                            \
            const long gb = gibase + (long)(brow0 + r) * 1536 + gcol;              \
            NXT_[r]     = Gi[gb];                                                  \
            NXT_[4 + r] = Gi[gb + 512];                                            \
            NXT_[8 + r] = Gi[gb + 1024];                                           \
          }                                                                        \
        }                                                                          \
        __syncthreads();                                                           \
        if (tid == 0)                                                              \
          __hip_atomic_store(&flags[cluster * CWG + slot], want,                   \
                             __ATOMIC_RELAXED, __HIP_MEMORY_SCOPE_AGENT);          \
        int v;                                                                     \
        do {                                                                       \
          v = __hip_atomic_load(&flags[cluster * CWG + (lane & 7)],                \
                                __ATOMIC_RELAXED, __HIP_MEMORY_SCOPE_AGENT);       \
        } while (!__all(v >= want));                                               \
        __atomic_signal_fence(__ATOMIC_SEQ_CST);                                   \
      }                                                                            \
    } else {                                                                       \
      _Pragma("unroll")                                                            \
      for (int r = 0; r < 4; ++r)                                                  \
        out[((long)t_ * 64 + brow0 + r) * 512 + gcol] = hprev[r];                  \
    }                                                                              \
  } while (0)

// ---------------- K3: persistent recurrence ----------------
__launch_bounds__(256, 1)
__global__ void recurrent_kernel(char* __restrict__ ws,
                                 const float* __restrict__ h0,
                                 const float* __restrict__ bhn,
                                 float* __restrict__ out) {
  const unsigned short* WhT = (const unsigned short*)(ws + O_WHT);
  const unsigned short* Gi  = (const unsigned short*)(ws + O_GI);
  int* bar     = (int*)(ws + O_BAR);
  int* fflag   = bar;            // fast flags: line (c*8+s)*FSTRIDE
  int* flags   = bar + 512;      // [32] agent-mode monotonic flags
  int* tick    = bar + 544;      // [8] per-XCD claims
  int* arrived = bar + 552;
  int* tick2   = bar + 553;
  int* abortf  = bar + 555;
  int* arrive2 = bar + 556;
  // pcnt lines at bar + 576 + c*16

  const int tid = threadIdx.x;
  __shared__ int sdec[4];        // [0]=fastc, [1]=cluster, [2]=slot, [3]=mode

  // ---- one-time election: pick 4 XCDs, 8 WGs each (4 independent clusters) ----
  if (tid == 0) {
    const int xcc = (int)(__builtin_amdgcn_s_getreg((3 << 11) | 20)) & 7;  // HW_REG_XCC_ID
    const int slot = __hip_atomic_fetch_add(&tick[xcc], 1, __ATOMIC_SEQ_CST, __HIP_MEMORY_SCOPE_AGENT);
    __hip_atomic_fetch_add(arrived, 1, __ATOMIC_SEQ_CST, __HIP_MEMORY_SCOPE_AGENT);
    while (__hip_atomic_load(arrived, __ATOMIC_ACQUIRE, __HIP_MEMORY_SCOPE_AGENT) < NB_LAUNCH)
      __builtin_amdgcn_s_sleep(4);
    int cnts[8];
    for (int c = 0; c < 8; ++c)
      cnts[c] = __hip_atomic_load(&tick[c], __ATOMIC_ACQUIRE, __HIP_MEMORY_SCOPE_AGENT);
    // deterministic top-4 (ties -> lowest index); identical result in every WG
    int chosen[NCL]; bool used[8] = {false,false,false,false,false,false,false,false};
    for (int k = 0; k < NCL; ++k) {
      int best = -1, bi2 = 0;
      for (int c = 0; c < 8; ++c)
        if (!used[c] && cnts[c] > best) { best = cnts[c]; bi2 = c; }
      chosen[k] = bi2; used[bi2] = true;
    }
    const int fastc = (cnts[chosen[NCL - 1]] >= CWG) ? 1 : 0;
    int cl = -1, sl = -1;
    if (fastc) {
      for (int k = 0; k < NCL; ++k)
        if (xcc == chosen[k] && slot < CWG) { cl = k; sl = slot; }
    } else {
      const int s2 = __hip_atomic_fetch_add(tick2, 1, __ATOMIC_SEQ_CST, __HIP_MEMORY_SCOPE_AGENT);
      if (s2 < NWORK) { cl = s2 >> 3; sl = s2 & 7; }
    }
    sdec[0] = fastc; sdec[1] = cl; sdec[2] = sl;
  }
  __syncthreads();
  const int fastc   = sdec[0];
  const int cluster = sdec[1];   // batch rows [16*cluster, 16*cluster+16)
  const int slot    = sdec[2];   // columns [64*slot, 64*slot+64)
  if (cluster < 0) return;

  // ---- probe: verify same-L2 coherence within each cluster ----
  if (tid == 0) {
    int mode = 0;
    if (fastc) {
      int* pc = bar + 576 + cluster * 16;
      __hip_atomic_fetch_add(pc, 1, __ATOMIC_RELAXED, __HIP_MEMORY_SCOPE_WORKGROUP);
      int ok = 0;
      for (int it = 0; it < 200000; ++it) {
        int exp = CWG;
        if (__hip_atomic_compare_exchange_strong(pc, &exp, CWG,
                __ATOMIC_RELAXED, __ATOMIC_RELAXED, __HIP_MEMORY_SCOPE_WORKGROUP)) { ok = 1; break; }
      }
      if (!ok) __hip_atomic_fetch_add(abortf, 1, __ATOMIC_RELAXED, __HIP_MEMORY_SCOPE_AGENT);
      __hip_atomic_fetch_add(arrive2, 1, __ATOMIC_ACQ_REL, __HIP_MEMORY_SCOPE_AGENT);
      while (__hip_atomic_load(arrive2, __ATOMIC_ACQUIRE, __HIP_MEMORY_SCOPE_AGENT) < NWORK)
        __builtin_amdgcn_s_sleep(2);
      mode = (__hip_atomic_load(abortf, __ATOMIC_ACQUIRE, __HIP_MEMORY_SCOPE_AGENT) > 0) ? 0 : 1;
    }
    sdec[3] = mode;
  }
  __syncthreads();
  const int fast = sdec[3];

  const int wv   = tid >> 6;
  const int lane = tid & 63;
  const int quad = lane >> 4, l16 = lane & 15;
  const int gcol = slot * 64 + wv * 16 + l16;   // per-wave distinct 16-col slice
  const int brow0 = cluster * 16 + quad * 4;    // + r

  // Wh fragments -> registers, persistent for all 512 steps (per-wave slice).
  bhalf8 Bf[3][16];
#pragma unroll
  for (int gt = 0; gt < 3; ++gt) {
    const unsigned short* wp = WhT + (long)(gt * 512 + gcol) * 512;
#pragma unroll
    for (int ks = 0; ks < 16; ++ks)
      Bf[gt][ks] = *(const bhalf8*)(wp + ks * 32 + quad * 8);
  }
  const float bhn_v = bhn[gcol];

  float hprev[4];
#pragma unroll
  for (int r = 0; r < 4; ++r)
    hprev[r] = h0[(brow0 + r) * 512 + gcol];

  // Gi double-buffer (raw ushorts): giA holds step 0
  unsigned short giA[12], giB[12];
#pragma unroll
  for (int r = 0; r < 4; ++r) {
    const long gb = (long)(brow0 + r) * 1536 + gcol;
    giA[r]     = Gi[gb];
    giA[4 + r] = Gi[gb + 512];
    giA[8 + r] = Gi[gb + 1024];
  }

#pragma unroll 1
  for (int tt = 0; tt < T_STEPS; tt += 2) {
    GRU_STEP(tt,     giA, giB);
    GRU_STEP(tt + 1, giB, giA);
  }
}

extern "C" void kernel_launch(void* const* d_in, const int* in_sizes, int n_in,
                              void* d_out, int out_size, void* d_ws, size_t ws_size,
                              hipStream_t stream) {
  const float* x   = (const float*)d_in[0];
  const float* h0  = (const float*)d_in[1];
  const float* Wi  = (const float*)d_in[2];
  const float* Wh  = (const float*)d_in[3];
  const float* bi  = (const float*)d_in[4];
  const float* bhn = (const float*)d_in[5];
  float* out = (float*)d_out;
  char* ws = (char*)d_ws;
  if (ws_size < WS_NEED) return;

  prep_kernel<<<4096, 256, 0, stream>>>(x, h0, Wi, Wh, ws);
  gi_gemm<<<dim3(256, 12), 256, 0, stream>>>(
      (const unsigned short*)(ws + O_XB), (const unsigned short*)(ws + O_WIT),
      bi, (unsigned short*)(ws + O_GI));
  recurrent_kernel<<<NB_LAUNCH, 256, 0, stream>>>(ws, h0, bhn, out);
}

// Round 4
// 1588.853 us; speedup vs baseline: 1.2805x; 1.2805x over previous
//
#include <hip/hip_runtime.h>

// GRU scan: T=512, B=64, D=H=512.  out[t] = h_{t+1}, fp32 [T,B,H].
//
//  K1 prep:   cast x->bf16, transpose+cast Wi,Wh -> [3H][K] bf16, init Hseq[0], zero bar
//  K2 gi_gemm: Gi[T*B,3H] = Xb @ Wi + bi  (bf16 MFMA, 128x128 tiles), stored bf16
//  K3 recurrent: 4 independent clusters of 8 WGs (batch rows are independent).
//     Cluster c owns batch rows [16c,16c+16); WG slot s owns cols [64s,64s+64).
//     R4 (synthesis of R2-proven + R3 lessons):
//       - LDS staging RESTORED (R2-proven): 16KB h block via global_load_lds; each
//         L2 line fetched once per CU, A-frags from LDS.  NEW swizzle ^((row&15)<<5)
//         makes the b128 reads exactly 2 lanes/slot = conflict-FREE (m136).
//       - Gi prefetch: raw-ushort parity double-buffer (giA/giB), issued post-poll,
//         consumed at NEXT step's gates -> never on the publish path.
//       - Flag publish/poll: plain agent-scope relaxed store + LOAD-poll (no CAS):
//         no L2 line serialization, producer store lands immediately, no atomic
//         write-through traffic.  All 4 waves poll -> release barrier dropped.
//       - Tail order: h-drain barrier -> flag -> poll -> out stores -> Gi issue ->
//         (next step) stage -> barrier: ONE consolidated drain absorbs out+Gi+stage.
//     Probe verifies same-L2 coherence; timeout -> agent-scope fallback (proven).

#define T_STEPS 512
#define NWORK 32
#define CWG 8                 // WGs per cluster
#define NCL 4                 // clusters
#define NB_LAUNCH 256
#define FSTRIDE 16            // ints between flag lines (64 B)

typedef __attribute__((ext_vector_type(8))) short bhalf8;
typedef __attribute__((ext_vector_type(4))) float floatx4;

__device__ inline float bf2f(unsigned short u) {
  union { unsigned u; float f; } v; v.u = ((unsigned)u) << 16; return v.f;
}
__device__ inline unsigned short f2bf(float f) {
  union { float f; unsigned u; } v; v.f = f;
  unsigned x = v.u;
  return (unsigned short)((x + 0x7fffu + ((x >> 16) & 1u)) >> 16);
}

__device__ inline void gload_lds16(const void* g, void* l) {
  __builtin_amdgcn_global_load_lds(
      (const __attribute__((address_space(1))) void*)g,
      (__attribute__((address_space(3))) void*)l, 16, 0, 0);
}

// ---- workspace layout (bytes) ----
// bar ints (prep zeroes 1024):
//   fflag lines:  (c*8+s)*16, c<4,s<8  -> ints [0,512)
//   flags[32] (fallback, agent): [512,544)
//   tick[8]@544, arrived@552, tick2@553, abortf@555, arrive2@556
//   pcnt lines: 576 + c*16  (c<4)
#define O_BAR 0                    //  4096 B
#define O_HB  4096                 //  Hseq[0] = h0 cast: [64][512] bf16 = 65536
#define O_WIT 69632                //  WiT [1536][512] bf16 = 1572864
#define O_WHT 1642496              //  WhT [1536][512] bf16 = 1572864
#define O_GI  3215360              //  Gi [32768][1536] bf16 = 100663296
#define O_XB  103878656ULL         //  Xb [32768][512] bf16 = 33554432 ; after K2 dies,
                                   //  reused as Hseq[1..512] (512 x 65536 B)
#define WS_NEED 137433088ULL       //  ~131.1 MiB

__device__ inline unsigned short* HS(char* ws, int t) {   // h buffer for step t
  return (t == 0) ? (unsigned short*)(ws + O_HB)
                  : (unsigned short*)(ws + O_XB + (long)(t - 1) * 65536);
}

// ---------------- K1: prep ----------------
__global__ void prep_kernel(const float* __restrict__ x, const float* __restrict__ h0,
                            const float* __restrict__ Wi, const float* __restrict__ Wh,
                            char* __restrict__ ws) {
  unsigned short* Xb  = (unsigned short*)(ws + O_XB);
  unsigned short* WiT = (unsigned short*)(ws + O_WIT);
  unsigned short* WhT = (unsigned short*)(ws + O_WHT);
  unsigned short* Hb0 = (unsigned short*)(ws + O_HB);
  int* bar = (int*)(ws + O_BAR);
  const long NX = 16777216, NW = 786432, NH = 32768;
  const long total = NX + 2 * NW + NH + 1024;
  for (long i = (long)blockIdx.x * blockDim.x + threadIdx.x; i < total;
       i += (long)gridDim.x * blockDim.x) {
    if (i < NX) {
      Xb[i] = f2bf(x[i]);
    } else if (i < NX + NW) {
      long j = i - NX;                 // j = n*512 + k  (WiT[n][k] = Wi[k][n])
      long n = j >> 9, k = j & 511;
      WiT[j] = f2bf(Wi[k * 1536 + n]);
    } else if (i < NX + 2 * NW) {
      long j = i - NX - NW;
      long n = j >> 9, k = j & 511;
      WhT[j] = f2bf(Wh[k * 1536 + n]);
    } else if (i < NX + 2 * NW + NH) {
      long j = i - NX - 2 * NW;
      Hb0[j] = f2bf(h0[j]);
    } else {
      bar[i - (NX + 2 * NW + NH)] = 0;
    }
  }
}

// ---------------- K2: Gi = Xb @ Wi + bi  (bf16 -> bf16) ----------------
__global__ void gi_gemm(const unsigned short* __restrict__ Xb,
                        const unsigned short* __restrict__ WiT,
                        const float* __restrict__ bi,
                        unsigned short* __restrict__ Gi) {
  __shared__ unsigned short As[128 * 32];
  __shared__ unsigned short Bs[128 * 32];
  const int tid  = threadIdx.x;
  const int m0   = blockIdx.x * 128;
  const int n0   = blockIdx.y * 128;
  const int lane = tid & 63, wv = tid >> 6;
  const int quad = lane >> 4, l16 = lane & 15;
  const int wm = (wv & 1) * 64, wn = (wv >> 1) * 64;
  const int sr = tid >> 1, sc = (tid & 1) * 16;

  floatx4 acc[4][4] = {};

  for (int kb = 0; kb < 16; ++kb) {
    const int k0 = kb * 32;
    __syncthreads();
    *(bhalf8*)(&As[sr * 32 + sc])     = *(const bhalf8*)(&Xb[(long)(m0 + sr) * 512 + k0 + sc]);
    *(bhalf8*)(&As[sr * 32 + sc + 8]) = *(const bhalf8*)(&Xb[(long)(m0 + sr) * 512 + k0 + sc + 8]);
    *(bhalf8*)(&Bs[sr * 32 + sc])     = *(const bhalf8*)(&WiT[(long)(n0 + sr) * 512 + k0 + sc]);
    *(bhalf8*)(&Bs[sr * 32 + sc + 8]) = *(const bhalf8*)(&WiT[(long)(n0 + sr) * 512 + k0 + sc + 8]);
    __syncthreads();

    bhalf8 af[4], bf[4];
#pragma unroll
    for (int i = 0; i < 4; ++i)
      af[i] = *(const bhalf8*)(&As[(wm + i * 16 + l16) * 32 + quad * 8]);
#pragma unroll
    for (int j = 0; j < 4; ++j)
      bf[j] = *(const bhalf8*)(&Bs[(wn + j * 16 + l16) * 32 + quad * 8]);
#pragma unroll
    for (int i = 0; i < 4; ++i)
#pragma unroll
      for (int j = 0; j < 4; ++j)
        acc[i][j] = __builtin_amdgcn_mfma_f32_16x16x32_bf16(af[i], bf[j], acc[i][j], 0, 0, 0);
  }

#pragma unroll
  for (int i = 0; i < 4; ++i)
#pragma unroll
    for (int j = 0; j < 4; ++j) {
      const int col = n0 + wn + j * 16 + l16;
      const float bv = bi[col];
#pragma unroll
      for (int r = 0; r < 4; ++r) {
        const int row = m0 + wm + i * 16 + quad * 4 + r;
        Gi[(long)row * 1536 + col] = f2bf(acc[i][j][r] + bv);
      }
    }
}

// ---- one GRU time step (macro so CUR_/NXT_ keep static register indexing) ----
// Fast-path swizzle: LDS[row*1024 + Y] holds h byte (Y ^ ((row&15)<<5)) of row.
// Stage: src = row*1024 + ((lane*16) ^ ((row&15)<<5)), dest linear (required).
// Read:  byteoff = l16*1024 + ((quad*16 + ks*64) ^ ((l16&15)<<5)).
// Slot index = (quad + 4ks) ^ 2*l16 mod 32 -> exactly 2 lanes/slot = conflict-free.
#define GRU_STEP(T_, CUR_, NXT_) do {                                              \
    const int t_ = (T_);                                                           \
    const unsigned short* hin  = HS(ws, t_);                                       \
    unsigned short*       hout = HS(ws, t_ + 1);                                   \
    bhalf8 af[16];                                                                 \
    if (fast) {                                                                    \
      const char* hbase = (const char*)hin + (size_t)cluster * 16384;              \
      _Pragma("unroll")                                                            \
      for (int it = 0; it < 4; ++it) {                                             \
        const int row = wv * 4 + it;            /* 0..15 within block */           \
        const char* src = hbase + row * 1024 + ((lane * 16) ^ ((row & 15) << 5));  \
        gload_lds16(src, &smem[row * 1024]);    /* dest linear: base+lane*16 */    \
      }                                                                            \
      __syncthreads();     /* drains stage (+ prev step's out/Gi, long done) */    \
      _Pragma("unroll")                                                            \
      for (int ks = 0; ks < 16; ++ks) {                                            \
        const int byteoff =                                                        \
            (l16 << 10) + (((ks << 6) + (quad << 4)) ^ ((l16 & 15) << 5));         \
        af[ks] = *(const bhalf8*)(&smem[byteoff]);                                 \
      }                                                                            \
    } else {                                                                       \
      const unsigned short* ap = hin + (cluster * 16 + l16) * 512 + quad * 8;      \
      _Pragma("unroll")                                                            \
      for (int ks = 0; ks < 16; ++ks) {                                            \
        union { unsigned long long q[2]; bhalf8 v; } u;                            \
        u.q[0] = __hip_atomic_load((const unsigned long long*)(ap + ks * 32),      \
                                   __ATOMIC_RELAXED, __HIP_MEMORY_SCOPE_AGENT);    \
        u.q[1] = __hip_atomic_load((const unsigned long long*)(ap + ks * 32) + 1,  \
                                   __ATOMIC_RELAXED, __HIP_MEMORY_SCOPE_AGENT);    \
        af[ks] = u.v;                                                              \
      }                                                                            \
    }                                                                              \
    floatx4 racc = {0.f, 0.f, 0.f, 0.f};                                           \
    floatx4 zacc = {0.f, 0.f, 0.f, 0.f};                                           \
    floatx4 nacc = {0.f, 0.f, 0.f, 0.f};                                           \
    _Pragma("unroll")                                                              \
    for (int ks = 0; ks < 16; ++ks) {                                              \
      racc = __builtin_amdgcn_mfma_f32_16x16x32_bf16(af[ks], Bf[0][ks], racc, 0, 0, 0);\
      zacc = __builtin_amdgcn_mfma_f32_16x16x32_bf16(af[ks], Bf[1][ks], zacc, 0, 0, 0);\
      nacc = __builtin_amdgcn_mfma_f32_16x16x32_bf16(af[ks], Bf[2][ks], nacc, 0, 0, 0);\
    }                                                                              \
    _Pragma("unroll")                                                              \
    for (int r = 0; r < 4; ++r) {                                                  \
      const float rg = 1.f / (1.f + __expf(-(bf2f(CUR_[r]) + racc[r])));           \
      const float zg = 1.f / (1.f + __expf(-(bf2f(CUR_[4 + r]) + zacc[r])));       \
      const float pre = bf2f(CUR_[8 + r]) + rg * (nacc[r] + bhn_v);                \
      const float e2 = __expf(2.f * pre);                                          \
      const float ng = 1.f - 2.f / (e2 + 1.f);      /* tanh */                     \
      const float hn = (1.f - zg) * ng + zg * hprev[r];                            \
      hprev[r] = hn;                                                               \
      const unsigned hb = (unsigned)f2bf(hn);                                      \
      const unsigned ob = __shfl_xor(hb, 1, 64);    /* partner col (l16^1) */      \
      if (!(l16 & 1)) {                                                            \
        unsigned* dst = (unsigned*)(hout + (brow0 + r) * 512 + gcol);              \
        const unsigned packed = hb | (ob << 16);                                   \
        if (fast) *dst = packed;                    /* write-through -> XCD L2 */  \
        else __hip_atomic_store(dst, packed, __ATOMIC_RELAXED,                     \
                                __HIP_MEMORY_SCOPE_AGENT);                         \
      }                                                                            \
    }                                                                              \
    if (t_ + 1 < T_STEPS) {                                                        \
      const int want = t_ + 1;                                                     \
      if (fast) {                                                                  \
        __syncthreads();               /* drains ONLY the 2KB h stores */          \
        if (tid == 0)                                                              \
          __hip_atomic_store(&fflag[(cluster * CWG + slot) * FSTRIDE], want,       \
                             __ATOMIC_RELAXED, __HIP_MEMORY_SCOPE_AGENT);          \
        /* all waves LOAD-poll the 8 producer flags (lanes 0..7) */                \
        {                                                                          \
          bool ok = (lane >= CWG);                                                 \
          while (!__all(ok)) {                                                     \
            if (!ok) {                                                             \
              const int v = __hip_atomic_load(                                     \
                  &fflag[(cluster * CWG + lane) * FSTRIDE],                        \
                  __ATOMIC_RELAXED, __HIP_MEMORY_SCOPE_AGENT);                     \
              ok = (v >= want);                                                    \
            }                                                                      \
          }                                                                        \
        }                                                                          \
        /* fire-and-forget: out stores + next Gi; drained at next stage-barrier */ \
        _Pragma("unroll")                                                          \
        for (int r = 0; r < 4; ++r)                                                \
          out[((long)t_ * 64 + brow0 + r) * 512 + gcol] = hprev[r];                \
        {                                                                          \
          const long gibase = (long)want * 64 * 1536;                              \
          _Pragma("unroll")                                                        \
          for (int r = 0; r < 4; ++r) {                                            \
            const long gb = gibase + (long)(brow0 + r) * 1536 + gcol;              \
            NXT_[r]     = Gi[gb];          /* raw ushorts: waitcnt lands at */     \
            NXT_[4 + r] = Gi[gb + 512];    /* NEXT step's gates            */      \
            NXT_[8 + r] = Gi[gb + 1024];                                           \
          }                                                                        \
        }                                                                          \
      } else {                                                                     \
        _Pragma("unroll")                                                          \
        for (int r = 0; r < 4; ++r)                                                \
          out[((long)t_ * 64 + brow0 + r) * 512 + gcol] = hprev[r];                \
        {                                                                          \
          const long gibase = (long)want * 64 * 1536;                              \
          _Pragma("unroll")                                                        \
          for (int r = 0; r < 4; ++r) {                                            \
            const long gb = gibase + (long)(brow0 + r) * 1536 + gcol;              \
            NXT_[r]     = Gi[gb];                                                  \
            NXT_[4 + r] = Gi[gb + 512];                                            \
            NXT_[8 + r] = Gi[gb + 1024];                                           \
          }                                                                        \
        }                                                                          \
        __syncthreads();                                                           \
        if (tid == 0)                                                              \
          __hip_atomic_store(&flags[cluster * CWG + slot], want,                   \
                             __ATOMIC_RELAXED, __HIP_MEMORY_SCOPE_AGENT);          \
        int v;                                                                     \
        do {                                                                       \
          v = __hip_atomic_load(&flags[cluster * CWG + (lane & 7)],                \
                                __ATOMIC_RELAXED, __HIP_MEMORY_SCOPE_AGENT);       \
        } while (!__all(v >= want));                                               \
        __atomic_signal_fence(__ATOMIC_SEQ_CST);                                   \
      }                                                                            \
    } else {                                                                       \
      _Pragma("unroll")                                                            \
      for (int r = 0; r < 4; ++r)                                                  \
        out[((long)t_ * 64 + brow0 + r) * 512 + gcol] = hprev[r];                  \
    }                                                                              \
  } while (0)

// ---------------- K3: persistent recurrence ----------------
__launch_bounds__(256, 1)
__global__ void recurrent_kernel(char* __restrict__ ws,
                                 const float* __restrict__ h0,
                                 const float* __restrict__ bhn,
                                 float* __restrict__ out) {
  const unsigned short* WhT = (const unsigned short*)(ws + O_WHT);
  const unsigned short* Gi  = (const unsigned short*)(ws + O_GI);
  int* bar     = (int*)(ws + O_BAR);
  int* fflag   = bar;            // fast flags: line (c*8+s)*FSTRIDE
  int* flags   = bar + 512;      // [32] agent-mode monotonic flags
  int* tick    = bar + 544;      // [8] per-XCD claims
  int* arrived = bar + 552;
  int* tick2   = bar + 553;
  int* abortf  = bar + 555;
  int* arrive2 = bar + 556;
  // pcnt lines at bar + 576 + c*16

  const int tid = threadIdx.x;
  __shared__ __align__(64) unsigned char smem[16384];   // one 16-row h block
  __shared__ int sdec[4];        // [0]=fastc, [1]=cluster, [2]=slot, [3]=mode

  // ---- one-time election: pick 4 XCDs, 8 WGs each (4 independent clusters) ----
  if (tid == 0) {
    const int xcc = (int)(__builtin_amdgcn_s_getreg((3 << 11) | 20)) & 7;  // HW_REG_XCC_ID
    const int slot = __hip_atomic_fetch_add(&tick[xcc], 1, __ATOMIC_SEQ_CST, __HIP_MEMORY_SCOPE_AGENT);
    __hip_atomic_fetch_add(arrived, 1, __ATOMIC_SEQ_CST, __HIP_MEMORY_SCOPE_AGENT);
    while (__hip_atomic_load(arrived, __ATOMIC_ACQUIRE, __HIP_MEMORY_SCOPE_AGENT) < NB_LAUNCH)
      __builtin_amdgcn_s_sleep(4);
    int cnts[8];
    for (int c = 0; c < 8; ++c)
      cnts[c] = __hip_atomic_load(&tick[c], __ATOMIC_ACQUIRE, __HIP_MEMORY_SCOPE_AGENT);
    // deterministic top-4 (ties -> lowest index); identical result in every WG
    int chosen[NCL]; bool used[8] = {false,false,false,false,false,false,false,false};
    for (int k = 0; k < NCL; ++k) {
      int best = -1, bi2 = 0;
      for (int c = 0; c < 8; ++c)
        if (!used[c] && cnts[c] > best) { best = cnts[c]; bi2 = c; }
      chosen[k] = bi2; used[bi2] = true;
    }
    const int fastc = (cnts[chosen[NCL - 1]] >= CWG) ? 1 : 0;
    int cl = -1, sl = -1;
    if (fastc) {
      for (int k = 0; k < NCL; ++k)
        if (xcc == chosen[k] && slot < CWG) { cl = k; sl = slot; }
    } else {
      const int s2 = __hip_atomic_fetch_add(tick2, 1, __ATOMIC_SEQ_CST, __HIP_MEMORY_SCOPE_AGENT);
      if (s2 < NWORK) { cl = s2 >> 3; sl = s2 & 7; }
    }
    sdec[0] = fastc; sdec[1] = cl; sdec[2] = sl;
  }
  __syncthreads();
  const int fastc   = sdec[0];
  const int cluster = sdec[1];   // batch rows [16*cluster, 16*cluster+16)
  const int slot    = sdec[2];   // columns [64*slot, 64*slot+64)
  if (cluster < 0) return;

  // ---- probe: verify same-L2 coherence within each cluster ----
  if (tid == 0) {
    int mode = 0;
    if (fastc) {
      int* pc = bar + 576 + cluster * 16;
      __hip_atomic_fetch_add(pc, 1, __ATOMIC_RELAXED, __HIP_MEMORY_SCOPE_WORKGROUP);
      int ok = 0;
      for (int it = 0; it < 200000; ++it) {
        int exp = CWG;
        if (__hip_atomic_compare_exchange_strong(pc, &exp, CWG,
                __ATOMIC_RELAXED, __ATOMIC_RELAXED, __HIP_MEMORY_SCOPE_WORKGROUP)) { ok = 1; break; }
      }
      if (!ok) __hip_atomic_fetch_add(abortf, 1, __ATOMIC_RELAXED, __HIP_MEMORY_SCOPE_AGENT);
      __hip_atomic_fetch_add(arrive2, 1, __ATOMIC_ACQ_REL, __HIP_MEMORY_SCOPE_AGENT);
      while (__hip_atomic_load(arrive2, __ATOMIC_ACQUIRE, __HIP_MEMORY_SCOPE_AGENT) < NWORK)
        __builtin_amdgcn_s_sleep(2);
      mode = (__hip_atomic_load(abortf, __ATOMIC_ACQUIRE, __HIP_MEMORY_SCOPE_AGENT) > 0) ? 0 : 1;
    }
    sdec[3] = mode;
  }
  __syncthreads();
  const int fast = sdec[3];

  const int wv   = tid >> 6;
  const int lane = tid & 63;
  const int quad = lane >> 4, l16 = lane & 15;
  const int gcol = slot * 64 + wv * 16 + l16;   // per-wave distinct 16-col slice
  const int brow0 = cluster * 16 + quad * 4;    // + r

  // Wh fragments -> registers, persistent for all 512 steps (per-wave slice).
  bhalf8 Bf[3][16];
#pragma unroll
  for (int gt = 0; gt < 3; ++gt) {
    const unsigned short* wp = WhT + (long)(gt * 512 + gcol) * 512;
#pragma unroll
    for (int ks = 0; ks < 16; ++ks)
      Bf[gt][ks] = *(const bhalf8*)(wp + ks * 32 + quad * 8);
  }
  const float bhn_v = bhn[gcol];

  float hprev[4];
#pragma unroll
  for (int r = 0; r < 4; ++r)
    hprev[r] = h0[(brow0 + r) * 512 + gcol];

  // Gi double-buffer (raw ushorts): giA holds step 0
  unsigned short giA[12], giB[12];
#pragma unroll
  for (int r = 0; r < 4; ++r) {
    const long gb = (long)(brow0 + r) * 1536 + gcol;
    giA[r]     = Gi[gb];
    giA[4 + r] = Gi[gb + 512];
    giA[8 + r] = Gi[gb + 1024];
  }

#pragma unroll 1
  for (int tt = 0; tt < T_STEPS; tt += 2) {
    GRU_STEP(tt,     giA, giB);
    GRU_STEP(tt + 1, giB, giA);
  }
}

extern "C" void kernel_launch(void* const* d_in, const int* in_sizes, int n_in,
                              void* d_out, int out_size, void* d_ws, size_t ws_size,
                              hipStream_t stream) {
  const float* x   = (const float*)d_in[0];
  const float* h0  = (const float*)d_in[1];
  const float* Wi  = (const float*)d_in[2];
  const float* Wh  = (const float*)d_in[3];
  const float* bi  = (const float*)d_in[4];
  const float* bhn = (const float*)d_in[5];
  float* out = (float*)d_out;
  char* ws = (char*)d_ws;
  if (ws_size < WS_NEED) return;

  prep_kernel<<<4096, 256, 0, stream>>>(x, h0, Wi, Wh, ws);
  gi_gemm<<<dim3(256, 12), 256, 0, stream>>>(
      (const unsigned short*)(ws + O_XB), (const unsigned short*)(ws + O_WIT),
      bi, (unsigned short*)(ws + O_GI));
  recurrent_kernel<<<NB_LAUNCH, 256, 0, stream>>>(ws, h0, bhn, out);
}

// Round 6
// 1547.838 us; speedup vs baseline: 1.3144x; 1.0265x over previous
//
#include <hip/hip_runtime.h>

// GRU scan: T=512, B=64, D=H=512.  out[t] = h_{t+1}, fp32 [T,B,H].
//
//  K1 prep:   cast x->bf16, transpose+cast Wi,Wh -> [3H][K] bf16, init Hseq[0], zero bar
//  K2 gi_gemm: Gi[T*B,3H] = Xb @ Wi + bi  (bf16 MFMA, 128x128 tiles), stored bf16
//  K3 recurrent: 4 independent clusters of 8 WGs (batch rows are independent).
//     Cluster c owns batch rows [16c,16c+16); WG slot s owns cols [64s,64s+64).
//     R6 (proven primitives only, one structural change = tail-barrier-free):
//       - Shared 16KB cooperative LDS staging + ONE __syncthreads/step (R2-proven;
//         R4-verified conflict-free XOR swizzle ^((row&15)<<5)).  Single buffer is
//         safe: poll guarantees all waves finished step-t smem reads before any
//         wave stages t+1.
//       - PER-WAVE flags (32/cluster, 16B apart): each wave publishes after its OWN
//         s_waitcnt vmcnt(0) on the 2KB hout stores (agent relaxed store, R4-proven);
//         consumers load-poll all 32 flags (agent relaxed load, R4-proven).  No
//         second barrier; cluster unblocks on the last WAVE, not the last WG barrier.
//       - Gi prefetched TWO steps ahead into the just-consumed register buffer
//         (issue after publish): ~2 steps of slack >> L3 latency; Gi is never on
//         any drain path.
//     Probe verifies same-L2 coherence; timeout -> agent-scope fallback (proven).

#define T_STEPS 512
#define NWORK 32
#define CWG 8                 // WGs per cluster
#define NCL 4                 // clusters
#define NB_LAUNCH 256
#define FSTRIDE 4             // ints between per-wave flag slots (16 B)

typedef __attribute__((ext_vector_type(8))) short bhalf8;
typedef __attribute__((ext_vector_type(4))) float floatx4;

__device__ inline float bf2f(unsigned short u) {
  union { unsigned u; float f; } v; v.u = ((unsigned)u) << 16; return v.f;
}
__device__ inline unsigned short f2bf(float f) {
  union { float f; unsigned u; } v; v.f = f;
  unsigned x = v.u;
  return (unsigned short)((x + 0x7fffu + ((x >> 16) & 1u)) >> 16);
}

__device__ inline void gload_lds16(const void* g, void* l) {
  __builtin_amdgcn_global_load_lds(
      (const __attribute__((address_space(1))) void*)g,
      (__attribute__((address_space(3))) void*)l, 16, 0, 0);
}

// ---- workspace layout (bytes) ----
// bar ints (prep zeroes 1024):
//   fflag per-wave slots: (c*32 + w)*4, c<4, w<32 -> ints [0,512)
//   flags[32] (fallback, agent): [512,544)
//   tick[8]@544, arrived@552, tick2@553, abortf@555, arrive2@556
//   pcnt lines: 576 + c*16  (c<4)
#define O_BAR 0                    //  4096 B
#define O_HB  4096                 //  Hseq[0] = h0 cast: [64][512] bf16 = 65536
#define O_WIT 69632                //  WiT [1536][512] bf16 = 1572864
#define O_WHT 1642496              //  WhT [1536][512] bf16 = 1572864
#define O_GI  3215360              //  Gi [32768][1536] bf16 = 100663296
#define O_XB  103878656ULL         //  Xb [32768][512] bf16 = 33554432 ; after K2 dies,
                                   //  reused as Hseq[1..512] (512 x 65536 B)
#define WS_NEED 137433088ULL       //  ~131.1 MiB

__device__ inline unsigned short* HS(char* ws, int t) {   // h buffer for step t
  return (t == 0) ? (unsigned short*)(ws + O_HB)
                  : (unsigned short*)(ws + O_XB + (long)(t - 1) * 65536);
}

// ---------------- K1: prep ----------------
__global__ void prep_kernel(const float* __restrict__ x, const float* __restrict__ h0,
                            const float* __restrict__ Wi, const float* __restrict__ Wh,
                            char* __restrict__ ws) {
  unsigned short* Xb  = (unsigned short*)(ws + O_XB);
  unsigned short* WiT = (unsigned short*)(ws + O_WIT);
  unsigned short* WhT = (unsigned short*)(ws + O_WHT);
  unsigned short* Hb0 = (unsigned short*)(ws + O_HB);
  int* bar = (int*)(ws + O_BAR);
  const long NX = 16777216, NW = 786432, NH = 32768;
  const long total = NX + 2 * NW + NH + 1024;
  for (long i = (long)blockIdx.x * blockDim.x + threadIdx.x; i < total;
       i += (long)gridDim.x * blockDim.x) {
    if (i < NX) {
      Xb[i] = f2bf(x[i]);
    } else if (i < NX + NW) {
      long j = i - NX;                 // j = n*512 + k  (WiT[n][k] = Wi[k][n])
      long n = j >> 9, k = j & 511;
      WiT[j] = f2bf(Wi[k * 1536 + n]);
    } else if (i < NX + 2 * NW) {
      long j = i - NX - NW;
      long n = j >> 9, k = j & 511;
      WhT[j] = f2bf(Wh[k * 1536 + n]);
    } else if (i < NX + 2 * NW + NH) {
      long j = i - NX - 2 * NW;
      Hb0[j] = f2bf(h0[j]);
    } else {
      bar[i - (NX + 2 * NW + NH)] = 0;
    }
  }
}

// ---------------- K2: Gi = Xb @ Wi + bi  (bf16 -> bf16) ----------------
__global__ void gi_gemm(const unsigned short* __restrict__ Xb,
                        const unsigned short* __restrict__ WiT,
                        const float* __restrict__ bi,
                        unsigned short* __restrict__ Gi) {
  __shared__ unsigned short As[128 * 32];
  __shared__ unsigned short Bs[128 * 32];
  const int tid  = threadIdx.x;
  const int m0   = blockIdx.x * 128;
  const int n0   = blockIdx.y * 128;
  const int lane = tid & 63, wv = tid >> 6;
  const int quad = lane >> 4, l16 = lane & 15;
  const int wm = (wv & 1) * 64, wn = (wv >> 1) * 64;
  const int sr = tid >> 1, sc = (tid & 1) * 16;

  floatx4 acc[4][4] = {};

  for (int kb = 0; kb < 16; ++kb) {
    const int k0 = kb * 32;
    __syncthreads();
    *(bhalf8*)(&As[sr * 32 + sc])     = *(const bhalf8*)(&Xb[(long)(m0 + sr) * 512 + k0 + sc]);
    *(bhalf8*)(&As[sr * 32 + sc + 8]) = *(const bhalf8*)(&Xb[(long)(m0 + sr) * 512 + k0 + sc + 8]);
    *(bhalf8*)(&Bs[sr * 32 + sc])     = *(const bhalf8*)(&WiT[(long)(n0 + sr) * 512 + k0 + sc]);
    *(bhalf8*)(&Bs[sr * 32 + sc + 8]) = *(const bhalf8*)(&WiT[(long)(n0 + sr) * 512 + k0 + sc + 8]);
    __syncthreads();

    bhalf8 af[4], bf[4];
#pragma unroll
    for (int i = 0; i < 4; ++i)
      af[i] = *(const bhalf8*)(&As[(wm + i * 16 + l16) * 32 + quad * 8]);
#pragma unroll
    for (int j = 0; j < 4; ++j)
      bf[j] = *(const bhalf8*)(&Bs[(wn + j * 16 + l16) * 32 + quad * 8]);
#pragma unroll
    for (int i = 0; i < 4; ++i)
#pragma unroll
      for (int j = 0; j < 4; ++j)
        acc[i][j] = __builtin_amdgcn_mfma_f32_16x16x32_bf16(af[i], bf[j], acc[i][j], 0, 0, 0);
  }

#pragma unroll
  for (int i = 0; i < 4; ++i)
#pragma unroll
    for (int j = 0; j < 4; ++j) {
      const int col = n0 + wn + j * 16 + l16;
      const float bv = bi[col];
#pragma unroll
      for (int r = 0; r < 4; ++r) {
        const int row = m0 + wm + i * 16 + quad * 4 + r;
        Gi[(long)row * 1536 + col] = f2bf(acc[i][j][r] + bv);
      }
    }
}

// ---- one GRU time step (macro: CUR_ = Gi regs consumed at t, then REFILLED t+2) ----
// Fast-path swizzle (R4-verified conflict-free): LDS[row*1024+Y] = h byte
// (Y ^ ((row&15)<<5)); stage src pre-swizzled, LDS dest linear (gload_lds req).
#define GRU_STEP(T_, CUR_) do {                                                    \
    const int t_ = (T_);                                                           \
    const unsigned short* hin  = HS(ws, t_);                                       \
    unsigned short*       hout = HS(ws, t_ + 1);                                   \
    bhalf8 af[16];                                                                 \
    if (fast) {                                                                    \
      const char* hbase = (const char*)hin + (size_t)cluster * 16384;              \
      _Pragma("unroll")                                                            \
      for (int it = 0; it < 4; ++it) {                                             \
        const int row = wv * 4 + it;            /* 0..15 within block */           \
        const char* src = hbase + row * 1024 + ((lane * 16) ^ ((row & 15) << 5));  \
        gload_lds16(src, &smem[row * 1024]);    /* dest linear: base+lane*16 */    \
      }                                                                            \
      __syncthreads();     /* drains own stage (+ old out/Gi, long done); joins */ \
      _Pragma("unroll")                                                            \
      for (int ks = 0; ks < 16; ++ks) {                                            \
        const int byteoff =                                                        \
            (l16 << 10) + (((ks << 6) + (quad << 4)) ^ ((l16 & 15) << 5));         \
        af[ks] = *(const bhalf8*)(&smem[byteoff]);                                 \
      }                                                                            \
    } else {                                                                       \
      const unsigned short* ap = hin + (cluster * 16 + l16) * 512 + quad * 8;      \
      _Pragma("unroll")                                                            \
      for (int ks = 0; ks < 16; ++ks) {                                            \
        union { unsigned long long q[2]; bhalf8 v; } u;                            \
        u.q[0] = __hip_atomic_load((const unsigned long long*)(ap + ks * 32),      \
                                   __ATOMIC_RELAXED, __HIP_MEMORY_SCOPE_AGENT);    \
        u.q[1] = __hip_atomic_load((const unsigned long long*)(ap + ks * 32) + 1,  \
                                   __ATOMIC_RELAXED, __HIP_MEMORY_SCOPE_AGENT);    \
        af[ks] = u.v;                                                              \
      }                                                                            \
    }                                                                              \
    floatx4 racc = {0.f, 0.f, 0.f, 0.f};                                           \
    floatx4 zacc = {0.f, 0.f, 0.f, 0.f};                                           \
    floatx4 nacc = {0.f, 0.f, 0.f, 0.f};                                           \
    _Pragma("unroll")                                                              \
    for (int ks = 0; ks < 16; ++ks) {                                              \
      racc = __builtin_amdgcn_mfma_f32_16x16x32_bf16(af[ks], Bf[0][ks], racc, 0, 0, 0);\
      zacc = __builtin_amdgcn_mfma_f32_16x16x32_bf16(af[ks], Bf[1][ks], zacc, 0, 0, 0);\
      nacc = __builtin_amdgcn_mfma_f32_16x16x32_bf16(af[ks], Bf[2][ks], nacc, 0, 0, 0);\
    }                                                                              \
    _Pragma("unroll")                                                              \
    for (int r = 0; r < 4; ++r) {                                                  \
      const float rg = 1.f / (1.f + __expf(-(bf2f(CUR_[r]) + racc[r])));           \
      const float zg = 1.f / (1.f + __expf(-(bf2f(CUR_[4 + r]) + zacc[r])));       \
      const float pre = bf2f(CUR_[8 + r]) + rg * (nacc[r] + bhn_v);                \
      const float e2 = __expf(2.f * pre);                                          \
      const float ng = 1.f - 2.f / (e2 + 1.f);      /* tanh */                     \
      const float hn = (1.f - zg) * ng + zg * hprev[r];                            \
      hprev[r] = hn;                                                               \
      const unsigned hb = (unsigned)f2bf(hn);                                      \
      const unsigned ob = __shfl_xor(hb, 1, 64);    /* partner col (l16^1) */      \
      if (!(l16 & 1)) {                                                            \
        unsigned* dst = (unsigned*)(hout + (brow0 + r) * 512 + gcol);              \
        const unsigned packed = hb | (ob << 16);                                   \
        if (fast) *dst = packed;                    /* write-through -> XCD L2 */  \
        else __hip_atomic_store(dst, packed, __ATOMIC_RELAXED,                     \
                                __HIP_MEMORY_SCOPE_AGENT);                         \
      }                                                                            \
    }                                                                              \
    if (t_ + 1 < T_STEPS) {                                                        \
      const int want = t_ + 1;                                                     \
      if (fast) {                                                                  \
        /* per-wave publish: own hout stores acked in L2, then own flag */         \
        asm volatile("s_waitcnt vmcnt(0)" ::: "memory");                           \
        if (lane == 0)                                                             \
          __hip_atomic_store(&fflag[(cluster * 32 + wslot) * FSTRIDE], want,       \
                             __ATOMIC_RELAXED, __HIP_MEMORY_SCOPE_AGENT);          \
        /* fire-and-forget: out stores + Gi(t+2) refill overlap the poll */        \
        _Pragma("unroll")                                                          \
        for (int r = 0; r < 4; ++r)                                                \
          out[((long)t_ * 64 + brow0 + r) * 512 + gcol] = hprev[r];                \
        if (t_ + 2 < T_STEPS) {                                                    \
          const long gibase = (long)(t_ + 2) * 64 * 1536;                          \
          _Pragma("unroll")                                                        \
          for (int r = 0; r < 4; ++r) {                                            \
            const long gb = gibase + (long)(brow0 + r) * 1536 + gcol;              \
            CUR_[r]     = Gi[gb];          /* 2-step slack >> L3 latency */        \
            CUR_[4 + r] = Gi[gb + 512];                                            \
            CUR_[8 + r] = Gi[gb + 1024];                                           \
          }                                                                        \
        }                                                                          \
        /* all waves load-poll the 32 per-wave flags (lanes 0..31) */              \
        {                                                                          \
          bool ok = (lane >= 32);                                                  \
          while (!__all(ok)) {                                                     \
            if (!ok) {                                                             \
              const int v = __hip_atomic_load(                                     \
                  &fflag[(cluster * 32 + lane) * FSTRIDE],                         \
                  __ATOMIC_RELAXED, __HIP_MEMORY_SCOPE_AGENT);                     \
              ok = (v >= want);                                                    \
            }                                                                      \
          }                                                                        \
        }                                                                          \
      } else {                                                                     \
        _Pragma("unroll")                                                          \
        for (int r = 0; r < 4; ++r)                                                \
          out[((long)t_ * 64 + brow0 + r) * 512 + gcol] = hprev[r];                \
        if (t_ + 2 < T_STEPS) {                                                    \
          const long gibase = (long)(t_ + 2) * 64 * 1536;                          \
          _Pragma("unroll")                                                        \
          for (int r = 0; r < 4; ++r) {                                            \
            const long gb = gibase + (long)(brow0 + r) * 1536 + gcol;              \
            CUR_[r]     = Gi[gb];                                                  \
            CUR_[4 + r] = Gi[gb + 512];                                            \
            CUR_[8 + r] = Gi[gb + 1024];                                           \
          }                                                                        \
        }                                                                          \
        __syncthreads();                                                           \
        if (tid == 0)                                                              \
          __hip_atomic_store(&flags[cluster * CWG + slot], want,                   \
                             __ATOMIC_RELAXED, __HIP_MEMORY_SCOPE_AGENT);          \
        int v;                                                                     \
        do {                                                                       \
          v = __hip_atomic_load(&flags[cluster * CWG + (lane & 7)],                \
                                __ATOMIC_RELAXED, __HIP_MEMORY_SCOPE_AGENT);       \
        } while (!__all(v >= want));                                               \
        __atomic_signal_fence(__ATOMIC_SEQ_CST);                                   \
      }                                                                            \
    } else {                                                                       \
      _Pragma("unroll")                                                            \
      for (int r = 0; r < 4; ++r)                                                  \
        out[((long)t_ * 64 + brow0 + r) * 512 + gcol] = hprev[r];                  \
    }                                                                              \
  } while (0)

// ---------------- K3: persistent recurrence ----------------
__launch_bounds__(256, 1)
__global__ void recurrent_kernel(char* __restrict__ ws,
                                 const float* __restrict__ h0,
                                 const float* __restrict__ bhn,
                                 float* __restrict__ out) {
  const unsigned short* WhT = (const unsigned short*)(ws + O_WHT);
  const unsigned short* Gi  = (const unsigned short*)(ws + O_GI);
  int* bar     = (int*)(ws + O_BAR);
  int* fflag   = bar;            // fast per-wave flags: (c*32+w)*FSTRIDE
  int* flags   = bar + 512;      // [32] agent-mode monotonic flags
  int* tick    = bar + 544;      // [8] per-XCD claims
  int* arrived = bar + 552;
  int* tick2   = bar + 553;
  int* abortf  = bar + 555;
  int* arrive2 = bar + 556;
  // pcnt lines at bar + 576 + c*16

  const int tid = threadIdx.x;
  __shared__ __align__(64) unsigned char smem[16384];   // one shared 16-row h block
  __shared__ int sdec[4];        // [0]=fastc, [1]=cluster, [2]=slot, [3]=mode

  // ---- one-time election: pick 4 XCDs, 8 WGs each (4 independent clusters) ----
  if (tid == 0) {
    const int xcc = (int)(__builtin_amdgcn_s_getreg((3 << 11) | 20)) & 7;  // HW_REG_XCC_ID
    const int slot = __hip_atomic_fetch_add(&tick[xcc], 1, __ATOMIC_SEQ_CST, __HIP_MEMORY_SCOPE_AGENT);
    __hip_atomic_fetch_add(arrived, 1, __ATOMIC_SEQ_CST, __HIP_MEMORY_SCOPE_AGENT);
    while (__hip_atomic_load(arrived, __ATOMIC_ACQUIRE, __HIP_MEMORY_SCOPE_AGENT) < NB_LAUNCH)
      __builtin_amdgcn_s_sleep(4);
    int cnts[8];
    for (int c = 0; c < 8; ++c)
      cnts[c] = __hip_atomic_load(&tick[c], __ATOMIC_ACQUIRE, __HIP_MEMORY_SCOPE_AGENT);
    // deterministic top-4 (ties -> lowest index); identical result in every WG
    int chosen[NCL]; bool used[8] = {false,false,false,false,false,false,false,false};
    for (int k = 0; k < NCL; ++k) {
      int best = -1, bi2 = 0;
      for (int c = 0; c < 8; ++c)
        if (!used[c] && cnts[c] > best) { best = cnts[c]; bi2 = c; }
      chosen[k] = bi2; used[bi2] = true;
    }
    const int fastc = (cnts[chosen[NCL - 1]] >= CWG) ? 1 : 0;
    int cl = -1, sl = -1;
    if (fastc) {
      for (int k = 0; k < NCL; ++k)
        if (xcc == chosen[k] && slot < CWG) { cl = k; sl = slot; }
    } else {
      const int s2 = __hip_atomic_fetch_add(tick2, 1, __ATOMIC_SEQ_CST, __HIP_MEMORY_SCOPE_AGENT);
      if (s2 < NWORK) { cl = s2 >> 3; sl = s2 & 7; }
    }
    sdec[0] = fastc; sdec[1] = cl; sdec[2] = sl;
  }
  __syncthreads();
  const int fastc   = sdec[0];
  const int cluster = sdec[1];   // batch rows [16*cluster, 16*cluster+16)
  const int slot    = sdec[2];   // columns [64*slot, 64*slot+64)
  if (cluster < 0) return;

  // ---- probe: verify same-L2 coherence within each cluster ----
  if (tid == 0) {
    int mode = 0;
    if (fastc) {
      int* pc = bar + 576 + cluster * 16;
      __hip_atomic_fetch_add(pc, 1, __ATOMIC_RELAXED, __HIP_MEMORY_SCOPE_WORKGROUP);
      int ok = 0;
      for (int it = 0; it < 200000; ++it) {
        int exp = CWG;
        if (__hip_atomic_compare_exchange_strong(pc, &exp, CWG,
                __ATOMIC_RELAXED, __ATOMIC_RELAXED, __HIP_MEMORY_SCOPE_WORKGROUP)) { ok = 1; break; }
      }
      if (!ok) __hip_atomic_fetch_add(abortf, 1, __ATOMIC_RELAXED, __HIP_MEMORY_SCOPE_AGENT);
      __hip_atomic_fetch_add(arrive2, 1, __ATOMIC_ACQ_REL, __HIP_MEMORY_SCOPE_AGENT);
      while (__hip_atomic_load(arrive2, __ATOMIC_ACQUIRE, __HIP_MEMORY_SCOPE_AGENT) < NWORK)
        __builtin_amdgcn_s_sleep(2);
      mode = (__hip_atomic_load(abortf, __ATOMIC_ACQUIRE, __HIP_MEMORY_SCOPE_AGENT) > 0) ? 0 : 1;
    }
    sdec[3] = mode;
  }
  __syncthreads();
  const int fast = sdec[3];
  __syncthreads();               // all waves have read sdec before smem reuse

  const int wv   = tid >> 6;
  const int lane = tid & 63;
  const int quad = lane >> 4, l16 = lane & 15;
  const int gcol = slot * 64 + wv * 16 + l16;   // per-wave distinct 16-col slice
  const int brow0 = cluster * 16 + quad * 4;    // + r
  const int wslot = slot * 4 + wv;              // per-wave flag index within cluster

  // Wh fragments -> registers, persistent for all 512 steps (per-wave slice).
  bhalf8 Bf[3][16];
#pragma unroll
  for (int gt = 0; gt < 3; ++gt) {
    const unsigned short* wp = WhT + (long)(gt * 512 + gcol) * 512;
#pragma unroll
    for (int ks = 0; ks < 16; ++ks)
      Bf[gt][ks] = *(const bhalf8*)(wp + ks * 32 + quad * 8);
  }
  const float bhn_v = bhn[gcol];

  float hprev[4];
#pragma unroll
  for (int r = 0; r < 4; ++r)
    hprev[r] = h0[(brow0 + r) * 512 + gcol];

  // Gi parity buffers, 2 steps deep: giA = Gi(0), giB = Gi(1)
  unsigned short giA[12], giB[12];
#pragma unroll
  for (int r = 0; r < 4; ++r) {
    const long gb = (long)(brow0 + r) * 1536 + gcol;
    giA[r]     = Gi[gb];
    giA[4 + r] = Gi[gb + 512];
    giA[8 + r] = Gi[gb + 1024];
    const long gb1 = gb + 64 * 1536;
    giB[r]     = Gi[gb1];
    giB[4 + r] = Gi[gb1 + 512];
    giB[8 + r] = Gi[gb1 + 1024];
  }

#pragma unroll 1
  for (int tt = 0; tt < T_STEPS; tt += 2) {
    GRU_STEP(tt,     giA);       // consume giA, refill with Gi(tt+2)
    GRU_STEP(tt + 1, giB);       // consume giB, refill with Gi(tt+3)
  }
}

extern "C" void kernel_launch(void* const* d_in, const int* in_sizes, int n_in,
                              void* d_out, int out_size, void* d_ws, size_t ws_size,
                              hipStream_t stream) {
  const float* x   = (const float*)d_in[0];
  const float* h0  = (const float*)d_in[1];
  const float* Wi  = (const float*)d_in[2];
  const float* Wh  = (const float*)d_in[3];
  const float* bi  = (const float*)d_in[4];
  const float* bhn = (const float*)d_in[5];
  float* out = (float*)d_out;
  char* ws = (char*)d_ws;
  if (ws_size < WS_NEED) return;

  prep_kernel<<<4096, 256, 0, stream>>>(x, h0, Wi, Wh, ws);
  gi_gemm<<<dim3(256, 12), 256, 0, stream>>>(
      (const unsigned short*)(ws + O_XB), (const unsigned short*)(ws + O_WIT),
      bi, (unsigned short*)(ws + O_GI));
  recurrent_kernel<<<NB_LAUNCH, 256, 0, stream>>>(ws, h0, bhn, out);
}